// Round 2
// baseline (565.172 us; speedup 1.0000x reference)
//
#include <hip/hip_runtime.h>
#include <hip/hip_bf16.h>

#define C 128
#define RBFD 20
#define NATOMS 50000
#define SCAN_CHUNK 1024

// ---------------------------------------------------------------------------
// Kernel 1: transpose W1, W2 (C x C, row-major [out][in]) into [in][out]
// ---------------------------------------------------------------------------
__global__ void transpose_w_kernel(const float* __restrict__ W1,
                                   const float* __restrict__ W2,
                                   float* __restrict__ W1T,
                                   float* __restrict__ W2T) {
    int t = blockIdx.x * blockDim.x + threadIdx.x;
    if (t < C * C) {
        int k = t / C;   // in-channel
        int c = t % C;   // out-channel
        W1T[t] = W1[c * C + k];
        W2T[t] = W2[c * C + k];
    }
}

// ---------------------------------------------------------------------------
// CSR construction: histogram -> hierarchical exclusive scan -> perm fill
// ---------------------------------------------------------------------------
__global__ __launch_bounds__(256) void histogram_kernel(
    const int* __restrict__ idx, int* __restrict__ count, int E)
{
    int e = blockIdx.x * blockDim.x + threadIdx.x;
    if (e < E) atomicAdd(&count[idx[e]], 1);
}

// Per-chunk partial sums (chunk = 1024 counts). grid = nchunks, block = 256.
__global__ __launch_bounds__(256) void scan_partials_kernel(
    const int* __restrict__ count, int* __restrict__ partial, int n)
{
    __shared__ int sm[256];
    const int start = blockIdx.x * SCAN_CHUNK;
    int s = 0;
    for (int i = threadIdx.x; i < SCAN_CHUNK; i += 256) {
        int g = start + i;
        if (g < n) s += count[g];
    }
    sm[threadIdx.x] = s;
    __syncthreads();
    for (int off = 128; off > 0; off >>= 1) {
        if (threadIdx.x < off) sm[threadIdx.x] += sm[threadIdx.x + off];
        __syncthreads();
    }
    if (threadIdx.x == 0) partial[blockIdx.x] = sm[0];
}

// Serial scan of the (≤64) chunk partials; rewrites partial[] in place as
// exclusive chunk bases and writes base[n] = total.
__global__ void scan_chunkbase_kernel(int* __restrict__ partial,
                                      int* __restrict__ base,
                                      int nchunks, int n)
{
    if (threadIdx.x == 0 && blockIdx.x == 0) {
        int run = 0;
        for (int k = 0; k < nchunks; ++k) {
            int t = partial[k];
            partial[k] = run;
            run += t;
        }
        base[n] = run;
    }
}

// Per-chunk exclusive scan + chunk base; writes base[] and cursor[].
// grid = nchunks, block = 1024.
__global__ __launch_bounds__(1024) void scan_apply_kernel(
    const int* __restrict__ count, const int* __restrict__ chunk_base,
    int* __restrict__ base, int* __restrict__ cursor, int n)
{
    __shared__ int sm[SCAN_CHUNK];
    const int t = threadIdx.x;
    const int i = blockIdx.x * SCAN_CHUNK + t;
    int v = (i < n) ? count[i] : 0;
    sm[t] = v;
    __syncthreads();
    for (int off = 1; off < SCAN_CHUNK; off <<= 1) {
        int tmp = (t >= off) ? sm[t - off] : 0;
        __syncthreads();
        sm[t] += tmp;
        __syncthreads();
    }
    if (i < n) {
        int excl = sm[t] - v + chunk_base[blockIdx.x];
        base[i] = excl;
        cursor[i] = excl;
    }
}

__global__ __launch_bounds__(256) void fill_perm_kernel(
    const int* __restrict__ idx, int* __restrict__ cursor,
    int* __restrict__ perm, int E)
{
    int e = blockIdx.x * blockDim.x + threadIdx.x;
    if (e < E) {
        int a = idx[e];
        int pos = atomicAdd(&cursor[a], 1);
        perm[pos] = e;
    }
}

// ---------------------------------------------------------------------------
// Gather kernel: 2 atoms per 256-thread block, thread = channel.
// Per edge: filter_c = dot(Wrbf[c], rbf[e]) + b, acc_c += filter*env*x[e][c].
// No atomics; acc written exactly once.
// ---------------------------------------------------------------------------
__global__ __launch_bounds__(256) void gather_kernel(
    const float* __restrict__ x,       // [E][C]
    const float* __restrict__ rbf,     // [E][RBFD]
    const float* __restrict__ env,     // [E]
    const int*   __restrict__ perm,    // [E]
    const int*   __restrict__ base,    // [N+1]
    const float* __restrict__ Wrbf,    // [C][RBFD]
    const float* __restrict__ brbf,    // [C]
    float* __restrict__ acc,           // [N][C]
    int natoms)
{
    const int tid = threadIdx.x;
    const int c   = tid & (C - 1);
    const int a   = blockIdx.x * 2 + (tid >> 7);
    if (a >= natoms) return;

    float w[RBFD];
#pragma unroll
    for (int r = 0; r < RBFD; ++r) w[r] = Wrbf[c * RBFD + r];
    const float bias = brbf[c];

    const int s0 = base[a], s1 = base[a + 1];
    float sum = 0.0f;
    for (int p = s0; p < s1; ++p) {
        const int e = perm[p];
        const float4* r4 = reinterpret_cast<const float4*>(rbf + (size_t)e * RBFD);
        float4 rv0 = r4[0], rv1 = r4[1], rv2 = r4[2], rv3 = r4[3], rv4 = r4[4];

        float f = bias;
        f = fmaf(rv0.x, w[0], f);  f = fmaf(rv0.y, w[1], f);
        f = fmaf(rv0.z, w[2], f);  f = fmaf(rv0.w, w[3], f);
        f = fmaf(rv1.x, w[4], f);  f = fmaf(rv1.y, w[5], f);
        f = fmaf(rv1.z, w[6], f);  f = fmaf(rv1.w, w[7], f);
        f = fmaf(rv2.x, w[8], f);  f = fmaf(rv2.y, w[9], f);
        f = fmaf(rv2.z, w[10], f); f = fmaf(rv2.w, w[11], f);
        f = fmaf(rv3.x, w[12], f); f = fmaf(rv3.y, w[13], f);
        f = fmaf(rv3.z, w[14], f); f = fmaf(rv3.w, w[15], f);
        f = fmaf(rv4.x, w[16], f); f = fmaf(rv4.y, w[17], f);
        f = fmaf(rv4.z, w[18], f); f = fmaf(rv4.w, w[19], f);

        sum = fmaf(f * env[e], x[(size_t)e * C + c], sum);
    }
    acc[(size_t)a * C + c] = sum;
}

// ---------------------------------------------------------------------------
// Fused MLP head (unchanged from round 1).
// ---------------------------------------------------------------------------
__device__ __forceinline__ float silu_f(float v) {
    return v * (1.0f / (1.0f + __expf(-v)));
}

__global__ __launch_bounds__(256) void mlp_head_kernel(
    const float* __restrict__ acc,   // [N][C]
    const float* __restrict__ W1T,   // [C][C]  (k-major)
    const float* __restrict__ b1,    // [C]
    const float* __restrict__ W2T,   // [C][C]
    const float* __restrict__ b2,    // [C]
    const float* __restrict__ W3,    // [1][C]
    const float* __restrict__ b3,    // [1]
    float* __restrict__ out,         // [N]
    int natoms)
{
    __shared__ float As[C][C + 1];

    const int tid = threadIdx.x;
    const int a0  = blockIdx.x * C;
    const int tc  = tid & 15;
    const int ta  = tid >> 4;
    const int abase = ta * 8;
    const int cbase = tc * 8;

    {
        const int sub = tid >> 7;
        const int k   = tid & 127;
        for (int pair = 0; pair < 64; ++pair) {
            const int al = pair * 2 + sub;
            const int a  = a0 + al;
            float v = (a < natoms) ? acc[(size_t)a * C + k] : 0.0f;
            As[k][al] = v;
        }
    }
    __syncthreads();

    float r[8][8];

    // layer 1
#pragma unroll
    for (int i = 0; i < 8; ++i)
#pragma unroll
        for (int j = 0; j < 8; ++j) r[i][j] = 0.0f;

#pragma unroll 2
    for (int k = 0; k < C; ++k) {
        float4 bq0 = *reinterpret_cast<const float4*>(W1T + k * C + cbase);
        float4 bq1 = *reinterpret_cast<const float4*>(W1T + k * C + cbase + 4);
        float bv[8] = {bq0.x, bq0.y, bq0.z, bq0.w, bq1.x, bq1.y, bq1.z, bq1.w};
        float av[8];
#pragma unroll
        for (int i = 0; i < 8; ++i) av[i] = As[k][abase + i];
#pragma unroll
        for (int i = 0; i < 8; ++i)
#pragma unroll
            for (int j = 0; j < 8; ++j) r[i][j] = fmaf(av[i], bv[j], r[i][j]);
    }

    __syncthreads();
    {
        float bb[8];
#pragma unroll
        for (int j = 0; j < 8; ++j) bb[j] = b1[cbase + j];
#pragma unroll
        for (int i = 0; i < 8; ++i)
#pragma unroll
            for (int j = 0; j < 8; ++j)
                As[cbase + j][abase + i] = silu_f(r[i][j] + bb[j]);
    }
    __syncthreads();

    // layer 2
#pragma unroll
    for (int i = 0; i < 8; ++i)
#pragma unroll
        for (int j = 0; j < 8; ++j) r[i][j] = 0.0f;

#pragma unroll 2
    for (int k = 0; k < C; ++k) {
        float4 bq0 = *reinterpret_cast<const float4*>(W2T + k * C + cbase);
        float4 bq1 = *reinterpret_cast<const float4*>(W2T + k * C + cbase + 4);
        float bv[8] = {bq0.x, bq0.y, bq0.z, bq0.w, bq1.x, bq1.y, bq1.z, bq1.w};
        float av[8];
#pragma unroll
        for (int i = 0; i < 8; ++i) av[i] = As[k][abase + i];
#pragma unroll
        for (int i = 0; i < 8; ++i)
#pragma unroll
            for (int j = 0; j < 8; ++j) r[i][j] = fmaf(av[i], bv[j], r[i][j]);
    }

    __syncthreads();

    // final: silu(.. + b2) . W3
    {
        float bb[8], w3v[8];
#pragma unroll
        for (int j = 0; j < 8; ++j) bb[j] = b2[cbase + j];
        float4 wq0 = *reinterpret_cast<const float4*>(W3 + cbase);
        float4 wq1 = *reinterpret_cast<const float4*>(W3 + cbase + 4);
        w3v[0]=wq0.x; w3v[1]=wq0.y; w3v[2]=wq0.z; w3v[3]=wq0.w;
        w3v[4]=wq1.x; w3v[5]=wq1.y; w3v[6]=wq1.z; w3v[7]=wq1.w;

#pragma unroll
        for (int i = 0; i < 8; ++i) {
            float p = 0.0f;
#pragma unroll
            for (int j = 0; j < 8; ++j)
                p = fmaf(silu_f(r[i][j] + bb[j]), w3v[j], p);
            As[abase + i][tc] = p;
        }
    }
    __syncthreads();

    if (tid < C) {
        const int a = a0 + tid;
        if (a < natoms) {
            float s = 0.0f;
#pragma unroll
            for (int t = 0; t < 16; ++t) s += As[tid][t];
            out[a] = s + b3[0];
        }
    }
}

// ---------------------------------------------------------------------------
extern "C" void kernel_launch(void* const* d_in, const int* in_sizes, int n_in,
                              void* d_out, int out_size, void* d_ws, size_t ws_size,
                              hipStream_t stream) {
    const float* x      = (const float*)d_in[0];
    const float* rbf    = (const float*)d_in[1];
    const float* env    = (const float*)d_in[2];
    const int*   idx    = (const int*)  d_in[3];
    const float* Wrbf   = (const float*)d_in[5];
    const float* brbf   = (const float*)d_in[6];
    const float* W1     = (const float*)d_in[7];
    const float* b1     = (const float*)d_in[8];
    const float* W2     = (const float*)d_in[9];
    const float* b2     = (const float*)d_in[10];
    const float* W3     = (const float*)d_in[11];
    const float* b3     = (const float*)d_in[12];
    float*       out    = (float*)d_out;

    const int E = in_sizes[0] / C;        // 800000
    const int N = NATOMS;                 // 50000
    const int nchunks = (N + SCAN_CHUNK - 1) / SCAN_CHUNK;   // 49

    // workspace layout (floats/ints, 4B each)
    float* acc     = (float*)d_ws;                    // N*C        = 6.40M
    float* W1T     = acc + (size_t)N * C;             // C*C        = 16K
    float* W2T     = W1T + C * C;                     // C*C        = 16K
    int*   count   = (int*)(W2T + C * C);             // N
    int*   base    = count + N;                       // N+1
    int*   cursor  = base + (N + 1);                  // N
    int*   partial = cursor + N;                      // 64
    int*   perm    = partial + 64;                    // E
    // total ≈ 29.5 MB

    // zero histogram counters
    hipMemsetAsync(count, 0, (size_t)N * sizeof(int), stream);

    // transpose MLP weights
    transpose_w_kernel<<<(C * C + 255) / 256, 256, 0, stream>>>(W1, W2, W1T, W2T);

    // CSR build
    histogram_kernel<<<(E + 255) / 256, 256, 0, stream>>>(idx, count, E);
    scan_partials_kernel<<<nchunks, 256, 0, stream>>>(count, partial, N);
    scan_chunkbase_kernel<<<1, 64, 0, stream>>>(partial, base, nchunks, N);
    scan_apply_kernel<<<nchunks, SCAN_CHUNK, 0, stream>>>(count, partial, base, cursor, N);
    fill_perm_kernel<<<(E + 255) / 256, 256, 0, stream>>>(idx, cursor, perm, E);

    // gather: 2 atoms per block
    gather_kernel<<<(N + 1) / 2, 256, 0, stream>>>(x, rbf, env, perm, base,
                                                   Wrbf, brbf, acc, N);

    // MLP head
    const int tiles = (N + C - 1) / C;
    mlp_head_kernel<<<tiles, 256, 0, stream>>>(acc, W1T, b1, W2T, b2, W3, b3, out, N);
}